// Round 5
// baseline (417.001 us; speedup 1.0000x reference)
//
#include <hip/hip_runtime.h>

#define LOG2E 1.44269504088896340736f

typedef _Float16 f16;
typedef __attribute__((ext_vector_type(2))) _Float16 f16x2;
typedef __attribute__((ext_vector_type(2))) __fp16 fp16x2;
typedef __attribute__((ext_vector_type(4))) _Float16 f16x4;
typedef __attribute__((ext_vector_type(8))) _Float16 f16x8;
typedef __attribute__((ext_vector_type(4))) float f32x4;
typedef __attribute__((ext_vector_type(16))) float f32x16;
typedef __attribute__((ext_vector_type(8))) unsigned short us8;
typedef __attribute__((ext_vector_type(2))) int i32x2;

#define BB 32
#define SSX 2048
#define SSY 2048
#define DD 160
#define M_TOTAL (BB*SSX)   // 65536

#define PRS 168    // proj LDS row stride (f16)
#define VTRS 136   // proj V^T store buffer stride
#define RS 168     // flash K/Q LDS stride (pad-8: const-offset ds_reads)

__device__ __forceinline__ f32x4 mfma16(f16x8 a, f16x8 b, f32x4 c) {
  return __builtin_amdgcn_mfma_f32_16x16x32_f16(a, b, c, 0, 0, 0);
}

__device__ __forceinline__ f32x16 mfma32(f16x8 a, f16x8 b, f32x16 c) {
  return __builtin_amdgcn_mfma_f32_32x32x16_f16(a, b, c, 0, 0, 0);
}

// RTZ pack of two f32 -> u32 of 2 f16 (low = a). P in [0,1]: RTZ error ~2^-12, negligible.
__device__ __forceinline__ unsigned pk2rtz(float a, float b) {
  union { fp16x2 h; unsigned u; } x;
  x.h = __builtin_amdgcn_cvt_pkrtz(a, b);
  return x.u;
}

// ---- Projection (byte-identical to round 3) ----
__global__ __launch_bounds__(256, 3) void proj_kernel(
    const float* __restrict__ x, const float* __restrict__ y,
    const float* __restrict__ Wq, const float* __restrict__ bq,
    const float* __restrict__ Wk, const float* __restrict__ bk,
    const float* __restrict__ Wv, const float* __restrict__ bv,
    f16* __restrict__ Qw, f16* __restrict__ Kw, f16* __restrict__ Vtw)
{
  __shared__ __align__(16) f16 buf[160*PRS];   // 53760 B -> 3 blocks/CU
  const int t = threadIdx.x;
  const int wave = t >> 6;
  const int lane = t & 63;
  const int quad = lane >> 4;
  const int l16  = lane & 15;
  const int bid  = (blockIdx.x & 7) * 192 + (blockIdx.x >> 3);
  const int kind = bid % 3;          // 0=Q, 1=K, 2=V
  const int tile = bid / 3;
  const int row0 = tile * 128;
  const float* src  = (kind == 0) ? x  : y;
  const float* W    = (kind == 0) ? Wq : (kind == 1 ? Wk : Wv);
  const float* bias = (kind == 0) ? bq : (kind == 1 ? bk : bv);

  for (int i = 0; i < 20; ++i) {
    int idx = t + i*256;
    int r = idx / 40, c4 = idx % 40;
    float4 v = *(const float4*)&src[(size_t)(row0 + r)*DD + c4*4];
    f16x4 h = { (f16)v.x, (f16)v.y, (f16)v.z, (f16)v.w };
    *(f16x4*)&buf[r*PRS + c4*4] = h;
  }
  __syncthreads();
  f16x8 afr0[5], afr1[5];
  #pragma unroll
  for (int ks = 0; ks < 5; ++ks) {
    afr0[ks] = *(const f16x8*)&buf[(wave*32 + l16)*PRS + ks*32 + quad*8];
    afr1[ks] = *(const f16x8*)&buf[(wave*32 + 16 + l16)*PRS + ks*32 + quad*8];
  }
  __syncthreads();

  for (int i = 0; i < 25; ++i) {
    int idx = t + i*256;
    int r = idx / 40, c4 = idx % 40;
    float4 v = *(const float4*)&W[r*160 + c4*4];
    f16x4 h = { (f16)v.x, (f16)v.y, (f16)v.z, (f16)v.w };
    *(f16x4*)&buf[r*PRS + c4*4] = h;
  }
  __syncthreads();

  f32x4 acc0[10], acc1[10];
  #pragma unroll
  for (int nt = 0; nt < 10; ++nt) {
    float bs = bias[nt*16 + l16];
    acc0[nt] = (f32x4){bs,bs,bs,bs};
    acc1[nt] = (f32x4){bs,bs,bs,bs};
    #pragma unroll
    for (int ks = 0; ks < 5; ++ks) {
      f16x8 bfr = *(const f16x8*)&buf[(nt*16 + l16)*PRS + ks*32 + quad*8];
      acc0[nt] = mfma16(afr0[ks], bfr, acc0[nt]);
      acc1[nt] = mfma16(afr1[ks], bfr, acc1[nt]);
    }
  }
  __syncthreads();

  if (kind < 2) {
    f16* dst = (kind == 0) ? Qw : Kw;
    #pragma unroll
    for (int nt = 0; nt < 10; ++nt)
      #pragma unroll
      for (int r = 0; r < 4; ++r) {
        buf[(wave*32 + quad*4 + r)*PRS + nt*16 + l16]      = (f16)acc0[nt][r];
        buf[(wave*32 + 16 + quad*4 + r)*PRS + nt*16 + l16] = (f16)acc1[nt][r];
      }
    __syncthreads();
    for (int i = 0; i < 10; ++i) {
      int idx = t + i*256;
      int r = idx / 20, g = idx % 20;
      *(us8*)&dst[(size_t)(row0 + r)*DD + g*8] = *(const us8*)&buf[r*PRS + g*8];
    }
  } else {
    #pragma unroll
    for (int nt = 0; nt < 10; ++nt)
      #pragma unroll
      for (int r = 0; r < 4; ++r) {
        buf[(nt*16 + l16)*VTRS + wave*32 + quad*4 + r]      = (f16)acc0[nt][r];
        buf[(nt*16 + l16)*VTRS + wave*32 + 16 + quad*4 + r] = (f16)acc1[nt][r];
      }
    __syncthreads();
    const int b  = row0 / SSY;
    const int y0 = row0 % SSY;
    for (int i = 0; i < 10; ++i) {
      int idx = t + i*256;
      int d = idx / 16, yg = idx % 16;
      *(us8*)&Vtw[((size_t)b*DD + d)*SSY + y0 + yg*8] = *(const us8*)&buf[d*VTRS + yg*8];
    }
  }
}

// ---------------- Flash attention + residual ----------------
// 128 q-rows/block, 32 q-rows/wave. K double-buffered in LDS (pad-168, const
// offsets), ONE barrier per yc. V read DIRECT from global (L2/L3-resident;
// 16 blocks/XCD share each batch) -> Vt_lds deleted, LDS ops/wave/yc 50->25.
// P exchange via cvt_pkrtz + permlane32_swap (no cndmask/bpermute).

#define LOAD_K(yb) { \
  const f16* ksrc = Kw + ((size_t)b*SSY + (yb))*DD; \
  _Pragma("unroll") \
  for (int i = 0; i < 5; ++i) { \
    int idx = t + i*256; int r = idx/20, c = idx%20; \
    kreg[i] = *(const us8*)&ksrc[(size_t)r*DD + c*8]; \
  } \
}

#define STORE_K(cb) { \
  _Pragma("unroll") \
  for (int i = 0; i < 5; ++i) { \
    int idx = t + i*256; int r = idx/20, c = idx%20; \
    *(us8*)&K_lds[cb][r*RS + c*8] = kreg[i]; \
  } \
}

__global__ __launch_bounds__(256, 2) void flash_kernel(
    const f16* __restrict__ Qw, const f16* __restrict__ Kw, const f16* __restrict__ Vtw,
    const float* __restrict__ x, float* __restrict__ out)
{
  __shared__ __align__(16) f16 K_lds[2][64*RS];   // 2 x 21504 B = 43008 B
  const int t = threadIdx.x;
  const int wave = t >> 6;
  const int lane = t & 63;
  const int l31  = lane & 31;
  const int hi   = lane >> 5;
  // 512 blocks = 8 XCDs x 64: each XCD owns 4 complete batches (K/V L2 reuse)
  const int bid  = (blockIdx.x & 7) * 64 + (blockIdx.x >> 3);
  const int b    = bid >> 4;
  const int x0   = (bid & 15) * 128;

  us8 kreg[5];
  LOAD_K(0);   // chunk 0 in flight during Q staging

  // stage Q: 64 rows into buf0, 64 rows into buf1; each wave hoists its B-frags
  f16x8 qfr[10];
  const f16* qsrc = Qw + ((size_t)b*SSX + x0)*DD;
  #pragma unroll
  for (int i = 0; i < 5; ++i) {
    int idx = t + i*256; int r = idx/20, c = idx%20;
    *(us8*)&K_lds[0][r*RS + c*8] = *(const us8*)&qsrc[(size_t)r*DD + c*8];
  }
  __syncthreads();
  if ((wave >> 1) == 0) {
    const int base = (wave & 1)*32;
    #pragma unroll
    for (int s = 0; s < 10; ++s)
      qfr[s] = *(const f16x8*)&K_lds[0][(base + l31)*RS + s*16 + hi*8];
  }
  #pragma unroll
  for (int i = 0; i < 5; ++i) {
    int idx = t + i*256; int r = idx/20, c = idx%20;
    *(us8*)&K_lds[1][r*RS + c*8] = *(const us8*)&qsrc[(size_t)(64 + r)*DD + c*8];
  }
  __syncthreads();
  if ((wave >> 1) == 1) {
    const int base = (wave & 1)*32;
    #pragma unroll
    for (int s = 0; s < 10; ++s)
      qfr[s] = *(const f16x8*)&K_lds[1][(base + l31)*RS + s*16 + hi*8];
  }
  STORE_K(0);        // chunk 0 -> buf0 (waves 2/3 read buf1 concurrently: OK)
  LOAD_K(64);        // chunk 1 in flight
  __syncthreads();   // buf0 visible; all qfr reads complete

  f32x16 acc[5];
  #pragma unroll
  for (int i = 0; i < 5; ++i)
    #pragma unroll
    for (int r = 0; r < 16; ++r) acc[i][r] = 0.f;
  float m = -1e30f, l = 0.f;

  // V advancing per-lane pointers: row d = dt*32 + l31, col base hi*8 (+c*16 imm)
  const f16* vp0 = Vtw + (size_t)b*DD*SSY + (size_t)l31*SSY + hi*8;
  const f16* vp1 = vp0 + (size_t)32*SSY;
  const f16* vp2 = vp0 + (size_t)64*SSY;
  const f16* vp3 = vp0 + (size_t)96*SSY;
  const f16* vp4 = vp0 + (size_t)128*SSY;

  for (int yc = 0; yc < SSY/64; ++yc) {
    const int cur = yc & 1;

    // S^T = K Q^T from K_lds[cur]
    f32x16 S0, S1;
    #pragma unroll
    for (int r = 0; r < 16; ++r) { S0[r] = 0.f; S1[r] = 0.f; }
    __builtin_amdgcn_s_setprio(1);
    #pragma unroll
    for (int s = 0; s < 10; ++s) {
      f16x8 k0 = *(const f16x8*)&K_lds[cur][l31*RS + s*16 + hi*8];
      f16x8 k1 = *(const f16x8*)&K_lds[cur][(32 + l31)*RS + s*16 + hi*8];
      S0 = mfma32(k0, qfr[s], S0);
      S1 = mfma32(k1, qfr[s], S1);
    }
    __builtin_amdgcn_s_setprio(0);

    // V frags c=0,1 issued early (latency hidden under softmax)
    f16x8 vf[4][5];
    #pragma unroll
    for (int c = 0; c < 2; ++c) {
      vf[c][0] = *(const f16x8*)&vp0[c*16];
      vf[c][1] = *(const f16x8*)&vp1[c*16];
      vf[c][2] = *(const f16x8*)&vp2[c*16];
      vf[c][3] = *(const f16x8*)&vp3[c*16];
      vf[c][4] = *(const f16x8*)&vp4[c*16];
    }

    // double-buffer maintenance: store chunk yc+1, prefetch chunk yc+2
    if (yc < SSY/64 - 1) STORE_K(cur ^ 1);
    if (yc < SSY/64 - 2) LOAD_K((yc+2)*64);

    // row max (max3-shaped trees)
    float pmax = fmaxf(S0[0], S0[1]);
    #pragma unroll
    for (int r = 2; r < 16; r += 2) pmax = fmaxf(fmaxf(pmax, S0[r]), S0[r+1]);
    #pragma unroll
    for (int r = 0; r < 16; r += 2) pmax = fmaxf(fmaxf(pmax, S1[r]), S1[r+1]);
    pmax = fmaxf(pmax, __shfl_xor(pmax, 32));

    // defer-max: rescale only when max grows by > 8
    if (__any(pmax > m + 8.f)) {
      float n  = fmaxf(m, pmax);
      float sc = exp2f((m - n)*LOG2E);
      m = n; l *= sc;
      #pragma unroll
      for (int r = 0; r < 16; ++r) {
        float scq = __shfl(sc, (r&3) + 8*(r>>2) + 4*hi);
        #pragma unroll
        for (int dt = 0; dt < 5; ++dt) acc[dt][r] *= scq;
      }
    }

    // P = exp(S - m); l accumulates f32 row sum
    float lsum = 0.f;
    #pragma unroll
    for (int r = 0; r < 16; ++r) { S0[r] = exp2f((S0[r] - m)*LOG2E); lsum += S0[r]; }
    #pragma unroll
    for (int r = 0; r < 16; ++r) { S1[r] = exp2f((S1[r] - m)*LOG2E); lsum += S1[r]; }
    lsum += __shfl_xor(lsum, 32);
    l += lsum;

    // V frags c=2,3
    #pragma unroll
    for (int c = 2; c < 4; ++c) {
      vf[c][0] = *(const f16x8*)&vp0[c*16];
      vf[c][1] = *(const f16x8*)&vp1[c*16];
      vf[c][2] = *(const f16x8*)&vp2[c*16];
      vf[c][3] = *(const f16x8*)&vp3[c*16];
      vf[c][4] = *(const f16x8*)&vp4[c*16];
    }

    // pack P -> A-layout entirely in regs: cvt_pkrtz + permlane32_swap
    unsigned pw[4][4];
    #pragma unroll
    for (int c = 0; c < 4; ++c) {
      const int bo = (c & 1)*8;
      float s0 = (c < 2) ? S0[bo+0] : S1[bo+0];
      float s1 = (c < 2) ? S0[bo+1] : S1[bo+1];
      float s2 = (c < 2) ? S0[bo+2] : S1[bo+2];
      float s3 = (c < 2) ? S0[bo+3] : S1[bo+3];
      float s4 = (c < 2) ? S0[bo+4] : S1[bo+4];
      float s5 = (c < 2) ? S0[bo+5] : S1[bo+5];
      float s6 = (c < 2) ? S0[bo+6] : S1[bo+6];
      float s7 = (c < 2) ? S0[bo+7] : S1[bo+7];
      unsigned L0 = pk2rtz(s0, s1), L1 = pk2rtz(s2, s3);
      unsigned H0 = pk2rtz(s4, s5), H1 = pk2rtz(s6, s7);
      i32x2 r02 = __builtin_amdgcn_permlane32_swap((int)L0, (int)H0, false, false);
      i32x2 r13 = __builtin_amdgcn_permlane32_swap((int)L1, (int)H1, false, false);
      pw[c][0] = (unsigned)r02.x; pw[c][1] = (unsigned)r13.x;
      pw[c][2] = (unsigned)r02.y; pw[c][3] = (unsigned)r13.y;
    }

    // PV: acc += P V
    __builtin_amdgcn_s_setprio(1);
    #pragma unroll
    for (int c = 0; c < 4; ++c) {
      union { unsigned u[4]; f16x8 h; } ph;
      ph.u[0] = pw[c][0]; ph.u[1] = pw[c][1]; ph.u[2] = pw[c][2]; ph.u[3] = pw[c][3];
      #pragma unroll
      for (int dt = 0; dt < 5; ++dt)
        acc[dt] = mfma32(ph.h, vf[c][dt], acc[dt]);
    }
    __builtin_amdgcn_s_setprio(0);

    vp0 += 64; vp1 += 64; vp2 += 64; vp3 += 64; vp4 += 64;
    __syncthreads();   // buf[cur^1] stores visible for next iteration
  }

  // epilogue: out = acc/l + x ; acc reg r -> q = (r&3)+8*(r>>2)+4*hi, col d = dt*32+l31
  #pragma unroll
  for (int r = 0; r < 16; ++r) {
    int qr = (r&3) + 8*(r>>2) + 4*hi;
    float rl = 1.f / __shfl(l, qr);
    size_t rowoff = ((size_t)b*SSX + x0 + wave*32 + qr)*DD + l31;
    #pragma unroll
    for (int dt = 0; dt < 5; ++dt) {
      size_t o = rowoff + (size_t)dt*32;
      out[o] = acc[dt][r]*rl + x[o];
    }
  }
}

extern "C" void kernel_launch(void* const* d_in, const int* in_sizes, int n_in,
                              void* d_out, int out_size, void* d_ws, size_t ws_size,
                              hipStream_t stream) {
  const float* x  = (const float*)d_in[0];
  const float* y  = (const float*)d_in[1];
  const float* Wq = (const float*)d_in[2];
  const float* bq = (const float*)d_in[3];
  const float* Wk = (const float*)d_in[4];
  const float* bk = (const float*)d_in[5];
  const float* Wv = (const float*)d_in[6];
  const float* bv = (const float*)d_in[7];

  f16* Qw  = (f16*)d_ws;
  f16* Kw  = Qw + (size_t)M_TOTAL*DD;
  f16* Vtw = Kw + (size_t)M_TOTAL*DD;   // 63 MB of workspace total

  proj_kernel<<<1536, 256, 0, stream>>>(x, y, Wq, bq, Wk, bk, Wv, bv, Qw, Kw, Vtw);
  flash_kernel<<<512, 256, 0, stream>>>(Qw, Kw, Vtw, x, (float*)d_out);
}

// Round 6
// 290.328 us; speedup vs baseline: 1.4363x; 1.4363x over previous
//
#include <hip/hip_runtime.h>

#define LOG2E 1.44269504088896340736f

typedef _Float16 f16;
typedef __attribute__((ext_vector_type(2))) _Float16 f16x2;
typedef __attribute__((ext_vector_type(2))) __fp16 fp16x2;
typedef __attribute__((ext_vector_type(4))) _Float16 f16x4;
typedef __attribute__((ext_vector_type(8))) _Float16 f16x8;
typedef __attribute__((ext_vector_type(4))) float f32x4;
typedef __attribute__((ext_vector_type(16))) float f32x16;
typedef __attribute__((ext_vector_type(8))) unsigned short us8;
typedef __attribute__((ext_vector_type(2))) int i32x2;

#define BB 32
#define SSX 2048
#define SSY 2048
#define DD 160
#define M_TOTAL (BB*SSX)   // 65536

#define PRS 168    // proj LDS row stride (f16)
#define VTRS 136   // proj V^T store buffer stride
#define RS 168     // flash K/Q LDS stride (pad-8: const-offset ds_reads)

__device__ __forceinline__ f32x4 mfma16(f16x8 a, f16x8 b, f32x4 c) {
  return __builtin_amdgcn_mfma_f32_16x16x32_f16(a, b, c, 0, 0, 0);
}

__device__ __forceinline__ f32x16 mfma32(f16x8 a, f16x8 b, f32x16 c) {
  return __builtin_amdgcn_mfma_f32_32x32x16_f16(a, b, c, 0, 0, 0);
}

// RTZ pack of two f32 -> u32 of 2 f16 (low = a). P in [0,1]: RTZ error ~2^-12, negligible.
__device__ __forceinline__ unsigned pk2rtz(float a, float b) {
  union { fp16x2 h; unsigned u; } x;
  x.h = __builtin_amdgcn_cvt_pkrtz(a, b);
  return x.u;
}

// ---- W pre-conversion: fp32 -> f16 once (proj blocks then load f16, no VALU convert) ----
__global__ __launch_bounds__(256) void wcvt_kernel(
    const float* __restrict__ Wq, const float* __restrict__ Wk, const float* __restrict__ Wv,
    f16* __restrict__ Wf)
{
  int idx = blockIdx.x*256 + threadIdx.x;   // 75 blocks * 256 = 19200 float4 = 76800 floats
  int which = idx / 6400;                   // uniform per block (6400 % 256 == 0)
  int off   = idx % 6400;
  const float* src = (which == 0) ? Wq : (which == 1 ? Wk : Wv);
  float4 v = *(const float4*)&src[off*4];
  f16x4 h = { (f16)v.x, (f16)v.y, (f16)v.z, (f16)v.w };
  *(f16x4*)&Wf[which*25600 + off*4] = h;
}

// ---- Projection v2: kind 0 = Q (x tile), kind 1 = K+V fused (y tile staged once).
// W loaded as f16 (pre-converted) -> no per-block convert; A-frags hoisted once,
// reused for both K and V MFMA passes.
__global__ __launch_bounds__(256, 3) void proj_kernel(
    const float* __restrict__ x, const float* __restrict__ y,
    const float* __restrict__ bq, const float* __restrict__ bk, const float* __restrict__ bv,
    const f16* __restrict__ Wf,
    f16* __restrict__ Qw, f16* __restrict__ Kw, f16* __restrict__ Vtw)
{
  __shared__ __align__(16) f16 buf[160*PRS];   // 53760 B -> 3 blocks/CU
  const int t = threadIdx.x;
  const int wave = t >> 6;
  const int lane = t & 63;
  const int quad = lane >> 4;
  const int l16  = lane & 15;
  // 1024 blocks = 8 XCDs x 128, Q/KV interleaved for XCD load balance
  const int bid  = (blockIdx.x & 7) * 128 + (blockIdx.x >> 3);
  const int kind = bid & 1;          // 0 = Q, 1 = K+V
  const int tile = bid >> 1;
  const int row0 = tile * 128;
  const float* src = kind ? y : x;

  // stage 128x160 input tile fp32 -> f16
  for (int i = 0; i < 20; ++i) {
    int idx = t + i*256;
    int r = idx / 40, c4 = idx % 40;
    float4 v = *(const float4*)&src[(size_t)(row0 + r)*DD + c4*4];
    f16x4 h = { (f16)v.x, (f16)v.y, (f16)v.z, (f16)v.w };
    *(f16x4*)&buf[r*PRS + c4*4] = h;
  }
  __syncthreads();
  f16x8 afr0[5], afr1[5];
  #pragma unroll
  for (int ks = 0; ks < 5; ++ks) {
    afr0[ks] = *(const f16x8*)&buf[(wave*32 + l16)*PRS + ks*32 + quad*8];
    afr1[ks] = *(const f16x8*)&buf[(wave*32 + 16 + l16)*PRS + ks*32 + quad*8];
  }
  __syncthreads();

#define LOAD_W(mat) { \
  for (int i = 0; i < 13; ++i) { \
    int idx = t + i*256; \
    if (idx < 3200) { \
      int r = idx / 20, g = idx % 20; \
      *(us8*)&buf[r*PRS + g*8] = *(const us8*)&Wf[(mat)*25600 + r*160 + g*8]; \
    } \
  } }

#define MFMA_PASS(bias) { \
  _Pragma("unroll") \
  for (int nt = 0; nt < 10; ++nt) { \
    float bs = (bias)[nt*16 + l16]; \
    acc0[nt] = (f32x4){bs,bs,bs,bs}; \
    acc1[nt] = (f32x4){bs,bs,bs,bs}; \
    _Pragma("unroll") \
    for (int ks = 0; ks < 5; ++ks) { \
      f16x8 bfr = *(const f16x8*)&buf[(nt*16 + l16)*PRS + ks*32 + quad*8]; \
      acc0[nt] = mfma16(afr0[ks], bfr, acc0[nt]); \
      acc1[nt] = mfma16(afr1[ks], bfr, acc1[nt]); \
    } \
  } }

  f32x4 acc0[10], acc1[10];

  // ---- pass 1: Q (kind 0) or K (kind 1), row-major output
  LOAD_W(kind ? 1 : 0);
  __syncthreads();
  MFMA_PASS(kind ? bk : bq);
  __syncthreads();   // all waves done reading W from buf
  {
    f16* dst = kind ? Kw : Qw;
    #pragma unroll
    for (int nt = 0; nt < 10; ++nt)
      #pragma unroll
      for (int r = 0; r < 4; ++r) {
        buf[(wave*32 + quad*4 + r)*PRS + nt*16 + l16]      = (f16)acc0[nt][r];
        buf[(wave*32 + 16 + quad*4 + r)*PRS + nt*16 + l16] = (f16)acc1[nt][r];
      }
    __syncthreads();
    for (int i = 0; i < 10; ++i) {
      int idx = t + i*256;
      int r = idx / 20, g = idx % 20;
      *(us8*)&dst[(size_t)(row0 + r)*DD + g*8] = *(const us8*)&buf[r*PRS + g*8];
    }
  }
  if (!kind) return;   // uniform per block

  // ---- pass 2: V (afr still in registers), V^T output
  __syncthreads();     // out-store reads of buf complete before overwrite
  LOAD_W(2);
  __syncthreads();
  MFMA_PASS(bv);
  __syncthreads();
  {
    #pragma unroll
    for (int nt = 0; nt < 10; ++nt)
      #pragma unroll
      for (int r = 0; r < 4; ++r) {
        buf[(nt*16 + l16)*VTRS + wave*32 + quad*4 + r]      = (f16)acc0[nt][r];
        buf[(nt*16 + l16)*VTRS + wave*32 + 16 + quad*4 + r] = (f16)acc1[nt][r];
      }
    __syncthreads();
    const int b  = row0 / SSY;
    const int y0 = row0 % SSY;
    for (int i = 0; i < 10; ++i) {
      int idx = t + i*256;
      int d = idx / 16, yg = idx % 16;
      *(us8*)&Vtw[((size_t)b*DD + d)*SSY + y0 + yg*8] = *(const us8*)&buf[d*VTRS + yg*8];
    }
  }
}

// ---------------- Flash attention + residual: round-3 structure ----------------
// 128 q-rows/block, 32 q-rows/wave; K+V staged in LDS (pad-168 K, XOR-swizzled V),
// 2 barriers/yc; XCD-aware bid swizzle. Pack P via cvt_pkrtz + permlane32_swap.

#define LOAD_CHUNK(yb) { \
  const f16* ksrc = Kw + ((size_t)b*SSY + (yb))*DD; \
  const f16* vsrc = Vtw + (size_t)b*DD*SSY + (yb); \
  _Pragma("unroll") \
  for (int i = 0; i < 5; ++i) { \
    int idx = t + i*256; int r = idx/20, c = idx%20; \
    kreg[i] = *(const us8*)&ksrc[(size_t)r*DD + c*8]; \
  } \
  _Pragma("unroll") \
  for (int i = 0; i < 5; ++i) { \
    int idx = t + i*256; int d = idx>>3, g = idx&7; \
    vreg[i] = *(const us8*)&vsrc[(size_t)d*SSY + g*8]; \
  } \
}

#define STORE_CHUNK() { \
  _Pragma("unroll") \
  for (int i = 0; i < 5; ++i) { \
    int idx = t + i*256; int r = idx/20, c = idx%20; \
    *(us8*)&K_lds[r*RS + c*8] = kreg[i]; \
  } \
  _Pragma("unroll") \
  for (int i = 0; i < 5; ++i) { \
    int idx = t + i*256; int d = idx>>3, g = idx&7; \
    *(us8*)&Vt_lds[d*64 + ((g ^ (d & 7)) << 3)] = vreg[i]; \
  } \
}

__global__ __launch_bounds__(256, 2) void flash_kernel(
    const f16* __restrict__ Qw, const f16* __restrict__ Kw, const f16* __restrict__ Vtw,
    const float* __restrict__ x, float* __restrict__ out)
{
  __shared__ __align__(16) f16 K_lds[64*RS];      // 21504 B (also Q staging)
  __shared__ __align__(16) f16 Vt_lds[160*64];    // 20480 B -> total 41984 B
  const int t = threadIdx.x;
  const int wave = t >> 6;
  const int lane = t & 63;
  const int l31  = lane & 31;
  const int hi   = lane >> 5;
  // 512 blocks = 8 XCDs x 64: each XCD owns 4 complete batches (K/V L2 reuse)
  const int bid  = (blockIdx.x & 7) * 64 + (blockIdx.x >> 3);
  const int b    = bid >> 4;
  const int x0   = (bid & 15) * 128;

  us8 kreg[5], vreg[5];
  LOAD_CHUNK(0);   // overlap chunk-0 HBM latency with Q staging

  // stage Q (128 rows in two 64-row passes through K_lds), hoist B-frags (32 rows/wave)
  f16x8 qfr[10];
  #pragma unroll
  for (int h = 0; h < 2; ++h) {
    if (h) __syncthreads();
    const f16* qsrc = Qw + ((size_t)b*SSX + x0 + h*64)*DD;
    for (int i = 0; i < 5; ++i) {
      int idx = t + i*256;
      int r = idx / 20, c = idx % 20;
      *(us8*)&K_lds[r*RS + c*8] = *(const us8*)&qsrc[(size_t)r*DD + c*8];
    }
    __syncthreads();
    if ((wave >> 1) == h) {
      const int base = (wave & 1)*32;
      #pragma unroll
      for (int s = 0; s < 10; ++s)
        qfr[s] = *(const f16x8*)&K_lds[(base + l31)*RS + s*16 + hi*8];
    }
  }

  f32x16 acc[5];
  #pragma unroll
  for (int i = 0; i < 5; ++i)
    #pragma unroll
    for (int r = 0; r < 16; ++r) acc[i][r] = 0.f;
  float m = -1e30f, l = 0.f;

  for (int yc = 0; yc < SSY/64; ++yc) {
    __syncthreads();          // A: prev compute done reading LDS (and qfr reads at yc=0)
    STORE_CHUNK();
    __syncthreads();          // B: LDS visible
    if (yc < SSY/64 - 1) LOAD_CHUNK((yc+1)*64);   // overlaps compute below

    // S^T = K Q^T : rows = k (C-layout), cols = q = l31
    f32x16 S0, S1;
    #pragma unroll
    for (int r = 0; r < 16; ++r) { S0[r] = 0.f; S1[r] = 0.f; }
    __builtin_amdgcn_s_setprio(1);
    #pragma unroll
    for (int s = 0; s < 10; ++s) {
      f16x8 k0 = *(const f16x8*)&K_lds[l31*RS + s*16 + hi*8];
      f16x8 k1 = *(const f16x8*)&K_lds[(32 + l31)*RS + s*16 + hi*8];
      S0 = mfma32(k0, qfr[s], S0);
      S1 = mfma32(k1, qfr[s], S1);
    }
    __builtin_amdgcn_s_setprio(0);

    // row max (max3-shaped trees)
    float pmax = fmaxf(S0[0], S0[1]);
    #pragma unroll
    for (int r = 2; r < 16; r += 2) pmax = fmaxf(fmaxf(pmax, S0[r]), S0[r+1]);
    #pragma unroll
    for (int r = 0; r < 16; r += 2) pmax = fmaxf(fmaxf(pmax, S1[r]), S1[r+1]);
    pmax = fmaxf(pmax, __shfl_xor(pmax, 32));

    // defer-max: rescale only when max grows by > 8
    if (__any(pmax > m + 8.f)) {
      float n  = fmaxf(m, pmax);
      float sc = exp2f((m - n)*LOG2E);
      m = n; l *= sc;
      #pragma unroll
      for (int r = 0; r < 16; ++r) {
        float scq = __shfl(sc, (r&3) + 8*(r>>2) + 4*hi);
        #pragma unroll
        for (int dt = 0; dt < 5; ++dt) acc[dt][r] *= scq;
      }
    }

    // P = exp(S - m); l accumulates f32 row sum
    float lsum = 0.f;
    #pragma unroll
    for (int r = 0; r < 16; ++r) { S0[r] = exp2f((S0[r] - m)*LOG2E); lsum += S0[r]; }
    #pragma unroll
    for (int r = 0; r < 16; ++r) { S1[r] = exp2f((S1[r] - m)*LOG2E); lsum += S1[r]; }
    lsum += __shfl_xor(lsum, 32);
    l += lsum;

    // pack P -> A-layout in regs (cvt_pkrtz + permlane32_swap), then PV
    #pragma unroll
    for (int c = 0; c < 4; ++c) {
      const int bo = (c & 1)*8;
      float s0 = (c < 2) ? S0[bo+0] : S1[bo+0];
      float s1 = (c < 2) ? S0[bo+1] : S1[bo+1];
      float s2 = (c < 2) ? S0[bo+2] : S1[bo+2];
      float s3 = (c < 2) ? S0[bo+3] : S1[bo+3];
      float s4 = (c < 2) ? S0[bo+4] : S1[bo+4];
      float s5 = (c < 2) ? S0[bo+5] : S1[bo+5];
      float s6 = (c < 2) ? S0[bo+6] : S1[bo+6];
      float s7 = (c < 2) ? S0[bo+7] : S1[bo+7];
      unsigned L0 = pk2rtz(s0, s1), L1 = pk2rtz(s2, s3);
      unsigned H0 = pk2rtz(s4, s5), H1 = pk2rtz(s6, s7);
      i32x2 r02 = __builtin_amdgcn_permlane32_swap((int)L0, (int)H0, false, false);
      i32x2 r13 = __builtin_amdgcn_permlane32_swap((int)L1, (int)H1, false, false);
      union { unsigned u[4]; f16x8 h; } ph;
      ph.u[0] = (unsigned)r02.x; ph.u[1] = (unsigned)r13.x;
      ph.u[2] = (unsigned)r02.y; ph.u[3] = (unsigned)r13.y;
      __builtin_amdgcn_s_setprio(1);
      #pragma unroll
      for (int dt = 0; dt < 5; ++dt) {
        int row = dt*32 + l31;
        f16x8 vf = *(const f16x8*)&Vt_lds[row*64 + (((c*2 + hi) ^ (row & 7)) << 3)];
        acc[dt] = mfma32(ph.h, vf, acc[dt]);
      }
      __builtin_amdgcn_s_setprio(0);
    }
  }

  // epilogue: out = acc/l + x ; acc reg r -> q = (r&3)+8*(r>>2)+4*hi, col d = dt*32+l31
  #pragma unroll
  for (int r = 0; r < 16; ++r) {
    int qr = (r&3) + 8*(r>>2) + 4*hi;
    float rl = 1.f / __shfl(l, qr);
    size_t rowoff = ((size_t)b*SSX + x0 + wave*32 + qr)*DD + l31;
    #pragma unroll
    for (int dt = 0; dt < 5; ++dt) {
      size_t o = rowoff + (size_t)dt*32;
      out[o] = acc[dt][r]*rl + x[o];
    }
  }
}

extern "C" void kernel_launch(void* const* d_in, const int* in_sizes, int n_in,
                              void* d_out, int out_size, void* d_ws, size_t ws_size,
                              hipStream_t stream) {
  const float* x  = (const float*)d_in[0];
  const float* y  = (const float*)d_in[1];
  const float* Wq = (const float*)d_in[2];
  const float* bq = (const float*)d_in[3];
  const float* Wk = (const float*)d_in[4];
  const float* bk = (const float*)d_in[5];
  const float* Wv = (const float*)d_in[6];
  const float* bv = (const float*)d_in[7];

  f16* Qw  = (f16*)d_ws;
  f16* Kw  = Qw + (size_t)M_TOTAL*DD;
  f16* Vtw = Kw + (size_t)M_TOTAL*DD;   // 63 MB for Q/K/Vt
  // Wf (3 x 160x160 f16 = 153600 B) at top of workspace, 256B-aligned
  size_t wf_off = (ws_size - 153600) & ~(size_t)255;
  f16* Wf = (f16*)((char*)d_ws + wf_off);

  wcvt_kernel<<<75, 256, 0, stream>>>(Wq, Wk, Wv, Wf);
  proj_kernel<<<1024, 256, 0, stream>>>(x, y, bq, bk, bv, Wf, Qw, Kw, Vtw);
  flash_kernel<<<512, 256, 0, stream>>>(Qw, Kw, Vtw, x, (float*)d_out);
}